// Round 9
// baseline (9817.904 us; speedup 1.0000x reference)
//
#include <hip/hip_runtime.h>

typedef _Float16 h2_t  __attribute__((ext_vector_type(2)));
typedef _Float16 f16x8 __attribute__((ext_vector_type(8)));
typedef float    f32x4 __attribute__((ext_vector_type(4)));

#define HID  100
#define TENC 4096
#define TDEC 4096
#define NCLS 6
#define NTHR 256   // 4 waves, 1/SIMD: non-MAC VALU overhead paid ONCE per SIMD (v12 lesson)

__device__ __forceinline__ float sigm(float v)  { return __builtin_amdgcn_rcpf(1.0f + __expf(-v)); }
__device__ __forceinline__ float tanh_(float v) { return 1.0f - 2.0f * __builtin_amdgcn_rcpf(1.0f + __expf(2.0f * v)); }

#define SYNC_LDS() asm volatile("s_waitcnt lgkmcnt(0)\n\ts_barrier" ::: "memory")

__device__ __forceinline__ float packh2(float a, float b) {
    h2_t p; p[0] = (_Float16)a; p[1] = (_Float16)b;
    return __builtin_bit_cast(float, p);
}

// fdot2 shorthand
__device__ __forceinline__ float fd2(float w, float h, float acc) {
    return __builtin_amdgcn_fdot2(__builtin_bit_cast(h2_t, w),
                                  __builtin_bit_cast(h2_t, h), acc, false);
}

// xor-1 pair sum via DPP quad_perm [1,0,3,2] — PROVEN (v8, 3414us PASS).
__device__ __forceinline__ float xsum1(float v) {
    const int s = __builtin_amdgcn_update_dpp(
        0, __builtin_bit_cast(int, v), 0xB1, 0xF, 0xF, true);
    return v + __builtin_bit_cast(float, s);
}

// Persistent single-workgroup LSTM, v13 — 4-wave HYBRID (matrix k<64, VALU k 64..104).
// From v12's verified mapping (PASS, absmax 1.95e-3), re-hosted on 4 waves:
//  - MFMA: 7 tiles/wave x 2 ktiles = 14 MFMA -> 224cy matrix/SIMD, hidden
//    under VALU issue (same-wave ILP; m114).
//  - A-fill VERBATIM from v12: in-tile row col <-> gate=col&3, cellInTile=col>>2;
//    C/D quad of lane (col,lg) = 4 gates of cell 4*tile+lg (verified).
//  - VALU k-slice: cell owned by xor-1 LANE PAIR (ts=col>>1, slc=col&1,
//    cols 14/15 idle-zero); each lane 20k = 10 f16-pairs; pair-summed with
//    the proven quad_perm butterfly. Both pair lanes replicate c (v8 pattern).
//  - x/bias in k-slots 100..103 (VALU range), input staged per step by t==0.
//  - amdgpu_waves_per_eu(1,1): pins VGPR budget ~512 -> NO compiler squeeze
//    (v11/v12 got 84/60 and spilled to L2 scratch on the serial chain).
__global__ __launch_bounds__(NTHR, 1) __attribute__((amdgpu_waves_per_eu(1, 1)))
void lstm_rec(const float* __restrict__ x,      // [TENC*3]
              const int*   __restrict__ y,      // [TDEC]
              const float* __restrict__ eWih,   // [400*3]
              const float* __restrict__ eWhh,   // [400*HID]
              const float* __restrict__ ebih,
              const float* __restrict__ ebhh,
              const float* __restrict__ dWih,   // [400]
              const float* __restrict__ dWhh,
              const float* __restrict__ dbih,
              const float* __restrict__ dbhh,
              float* __restrict__ hsto)         // [(TDEC-1)*HID] decoder h history
{
    __shared__ __align__(16) _Float16 hbuf[2][128];  // [parity][k-slot]: 0-99 h, 100-103 input, rest 0
    __shared__ __align__(8)  uint2    xst[TENC];     // packed f16: {x0,x1},{x2,1}
    __shared__               unsigned yst[TDEC];     // packed f16: {yf,0}

    const int t   = threadIdx.x;
    const int w   = t >> 6;
    const int l   = t & 63;
    const int col = l & 15;     // A-row-in-tile / D-col
    const int lg  = l >> 4;     // k-chunk id (A/B); cell-in-tile (D)
    const int ts  = col >> 1;   // owned tile slot 0..7 (7 = dead)
    const int slc = col & 1;    // VALU k-slice of the owned cell
    const int cellV = 4*(7*w + ts) + lg;            // owned cell (ts<7)
    const bool vld  = (ts < 7) && (cellV < HID);    // live cell for VALU/weights
    const bool wrt  = vld && (slc == 0);            // unique writer per cell

    // ---- stage x (f16 pairs) and y (f16) into LDS; zero h buffers ----
    for (int i = t; i < TENC; i += NTHR) {
        const float a = x[3*i], b = x[3*i+1], cc = x[3*i+2];
        uint2 u;
        u.x = __builtin_bit_cast(unsigned, packh2(a, b));
        u.y = __builtin_bit_cast(unsigned, packh2(cc, 1.0f));
        xst[i] = u;
    }
    for (int i = t; i < TDEC; i += NTHR)
        yst[i] = __builtin_bit_cast(unsigned, packh2((float)y[i], 0.0f));
    if (t < 256) ((_Float16*)hbuf)[t] = (_Float16)0.0f;   // both parities
    __syncthreads();

    // x_0 into hbuf[0][100..103] (published by the SYNC_LDS below)
    if (t == 0) {
        uint2 u;
        u.x = __builtin_bit_cast(unsigned, packh2(x[0], x[1]));
        u.y = __builtin_bit_cast(unsigned, packh2(x[2], 1.0f));
        *(uint2*)&hbuf[0][100] = u;
    }

    // ---- encoder weights ----
    // MFMA A-fragments, k<64 (A-fill formula VERBATIM from verified v12)
    f16x8 wA[7][2];
    #pragma unroll
    for (int tt = 0; tt < 7; ++tt) {
        #pragma unroll
        for (int kt = 0; kt < 2; ++kt) {
            f16x8 a;
            #pragma unroll
            for (int j = 0; j < 8; ++j) {
                float v = 0.0f;
                const int cellA = 4*(7*w + tt) + (col >> 2);
                if (cellA < HID) {
                    const int k = 32*kt + 8*lg + j;           // < 64: Whh only
                    v = eWhh[((col & 3)*HID + cellA)*HID + k];
                }
                a[j] = (_Float16)v;
            }
            wA[tt][kt] = a;
        }
    }
    // VALU slice weights, k in [64+20*slc, 84+20*slc): wf[gate][10 pairs]
    float wf[4][10];
    #pragma unroll
    for (int g = 0; g < 4; ++g) {
        #pragma unroll
        for (int j = 0; j < 10; ++j) {
            float v0 = 0.0f, v1 = 0.0f;
            if (vld) {
                const int wr = g*HID + cellV;
                const int k0 = 64 + 20*slc + 2*j, k1 = k0 + 1;
                v0 = (k0 < HID) ? eWhh[wr*HID + k0]
                   : (k0 < 103) ? eWih[wr*3 + (k0 - 100)] : (ebih[wr] + ebhh[wr]);
                v1 = (k1 < HID) ? eWhh[wr*HID + k1]
                   : (k1 < 103) ? eWih[wr*3 + (k1 - 100)] : (ebih[wr] + ebhh[wr]);
            }
            wf[g][j] = packh2(v0, v1);
        }
    }
    SYNC_LDS();

    const bool t1 = (ts == 1), t2 = (ts == 2), t3 = (ts == 3),
               t4 = (ts == 4), t5 = (ts == 5), t6 = (ts == 6);
    const f32x4 ZZ = {0.0f, 0.0f, 0.0f, 0.0f};
    float c = 0.0f;
    int p = 0;

    // ================ encoder: 4096 steps ================
    for (int s = 0; s < TENC; ++s) {
        const f16x8* hb = (const f16x8*)hbuf[p];
        const f16x8 B0 = hb[0 + lg];                  // k  0..31
        const f16x8 B1 = hb[4 + lg];                  // k 32..63
        const float* hfl = (const float*)hbuf[p];
        float hp[10];
        #pragma unroll
        for (int j = 0; j < 10; ++j) hp[j] = hfl[32 + 10*slc + j];  // k 64+20slc..

        if (t == 0 && s + 1 < TENC)                   // prefetch x_{s+1}
            *(uint2*)&hbuf[p ^ 1][100] = xst[s + 1];

        // matrix pipe: k<64, 7 tiles
        f32x4 acc[7];
        #pragma unroll
        for (int tt = 0; tt < 7; ++tt) {
            f32x4 z = __builtin_amdgcn_mfma_f32_16x16x32_f16(wA[tt][0], B0, ZZ, 0, 0, 0);
            acc[tt]  = __builtin_amdgcn_mfma_f32_16x16x32_f16(wA[tt][1], B1, z, 0, 0, 0);
        }

        // vector pipe (overlaps MFMA): this lane's 20k slice of its cell
        float p0 = 0.0f, p1 = 0.0f, p2 = 0.0f, p3 = 0.0f;
        #pragma unroll
        for (int j = 0; j < 10; ++j) {
            p0 = fd2(wf[0][j], hp[j], p0);
            p1 = fd2(wf[1][j], hp[j], p1);
            p2 = fd2(wf[2][j], hp[j], p2);
            p3 = fd2(wf[3][j], hp[j], p3);
        }
        p0 = xsum1(p0); p1 = xsum1(p1); p2 = xsum1(p2); p3 = xsum1(p3);

        // static select of this lane's tile quad
        f32x4 q = acc[0];
        if (t1) q = acc[1];
        if (t2) q = acc[2];
        if (t3) q = acc[3];
        if (t4) q = acc[4];
        if (t5) q = acc[5];
        if (t6) q = acc[6];

        const float a0 = q[0] + p0, a1 = q[1] + p1, a2 = q[2] + p2, a3 = q[3] + p3;
        const float fi = sigm(a0), ff = sigm(a1), fg = tanh_(a2), fo = sigm(a3);
        c = ff * c + fi * fg;                 // replicated in both pair lanes
        const float hn = fo * tanh_(c);
        if (wrt)
            hbuf[p ^ 1][cellV] = (_Float16)hn;   // cellV<100 guard also protects input slots
        SYNC_LDS();
        p ^= 1;
    }

    // ================ transition: decoder input slot {yf0, 1, 0, 0} ================
    if (t == 0) {
        uint2 v;
        v.x = (yst[0] & 0xFFFFu) | 0x3C000000u;   // {yf0, f16(1.0)}
        v.y = 0u;
        *(uint2*)&hbuf[p][100] = v;
    }

    // ---- decoder weights (reuse wA/wf) ----
    #pragma unroll
    for (int tt = 0; tt < 7; ++tt) {
        #pragma unroll
        for (int kt = 0; kt < 2; ++kt) {
            f16x8 a;
            #pragma unroll
            for (int j = 0; j < 8; ++j) {
                float v = 0.0f;
                const int cellA = 4*(7*w + tt) + (col >> 2);
                if (cellA < HID) {
                    const int k = 32*kt + 8*lg + j;
                    v = dWhh[((col & 3)*HID + cellA)*HID + k];
                }
                a[j] = (_Float16)v;
            }
            wA[tt][kt] = a;
        }
    }
    #pragma unroll
    for (int g = 0; g < 4; ++g) {
        #pragma unroll
        for (int j = 0; j < 10; ++j) {
            float v0 = 0.0f, v1 = 0.0f;
            if (vld) {
                const int wr = g*HID + cellV;
                const int k0 = 64 + 20*slc + 2*j, k1 = k0 + 1;
                v0 = (k0 < HID) ? dWhh[wr*HID + k0]
                   : (k0 == 100) ? dWih[wr]
                   : (k0 == 101) ? (dbih[wr] + dbhh[wr]) : 0.0f;
                v1 = (k1 < HID) ? dWhh[wr*HID + k1]
                   : (k1 == 100) ? dWih[wr]
                   : (k1 == 101) ? (dbih[wr] + dbhh[wr]) : 0.0f;
            }
            wf[g][j] = packh2(v0, v1);
        }
    }
    SYNC_LDS();

    // ================ decoder: 4095 steps (ratio==1 -> teacher-forced) ================
    for (int s = 0; s < TDEC - 1; ++s) {
        const f16x8* hb = (const f16x8*)hbuf[p];
        const f16x8 B0 = hb[0 + lg];
        const f16x8 B1 = hb[4 + lg];
        const float* hfl = (const float*)hbuf[p];
        float hp[10];
        #pragma unroll
        for (int j = 0; j < 10; ++j) hp[j] = hfl[32 + 10*slc + j];

        if (t == 0 && s + 1 < TDEC - 1) {
            uint2 v;
            v.x = (yst[s + 1] & 0xFFFFu) | 0x3C000000u;
            v.y = 0u;
            *(uint2*)&hbuf[p ^ 1][100] = v;
        }

        f32x4 acc[7];
        #pragma unroll
        for (int tt = 0; tt < 7; ++tt) {
            f32x4 z = __builtin_amdgcn_mfma_f32_16x16x32_f16(wA[tt][0], B0, ZZ, 0, 0, 0);
            acc[tt]  = __builtin_amdgcn_mfma_f32_16x16x32_f16(wA[tt][1], B1, z, 0, 0, 0);
        }

        float p0 = 0.0f, p1 = 0.0f, p2 = 0.0f, p3 = 0.0f;
        #pragma unroll
        for (int j = 0; j < 10; ++j) {
            p0 = fd2(wf[0][j], hp[j], p0);
            p1 = fd2(wf[1][j], hp[j], p1);
            p2 = fd2(wf[2][j], hp[j], p2);
            p3 = fd2(wf[3][j], hp[j], p3);
        }
        p0 = xsum1(p0); p1 = xsum1(p1); p2 = xsum1(p2); p3 = xsum1(p3);

        f32x4 q = acc[0];
        if (t1) q = acc[1];
        if (t2) q = acc[2];
        if (t3) q = acc[3];
        if (t4) q = acc[4];
        if (t5) q = acc[5];
        if (t6) q = acc[6];

        const float a0 = q[0] + p0, a1 = q[1] + p1, a2 = q[2] + p2, a3 = q[3] + p3;
        const float fi = sigm(a0), ff = sigm(a1), fg = tanh_(a2), fo = sigm(a3);
        c = ff * c + fi * fg;
        const float hn = fo * tanh_(c);
        if (wrt) {
            hbuf[p ^ 1][cellV] = (_Float16)hn;
            hsto[s * HID + cellV] = hn;       // global store, never fenced in-loop
        }
        SYNC_LDS();
        p ^= 1;
    }
    // kernel end-of-dispatch drains the hsto stores before logits_k launches
}

// Parallel logits: out[t][r] = linW[r] . h_t + linb[r], last row zeroed.
__global__ __launch_bounds__(256)
void logits_k(const float* __restrict__ hsto, const float* __restrict__ linW,
              const float* __restrict__ linb, float* __restrict__ out)
{
    const int idx = blockIdx.x * 256 + threadIdx.x;
    if (idx >= TDEC * NCLS) return;
    const int tt = idx / NCLS;
    const int r  = idx % NCLS;
    if (tt >= TDEC - 1) { out[idx] = 0.0f; return; }
    const float* h  = hsto + tt * HID;
    const float* wr = linW + r * HID;
    float a = linb[r];
    #pragma unroll 4
    for (int k = 0; k < HID; ++k) a += wr[k] * h[k];
    out[idx] = a;
}

extern "C" void kernel_launch(void* const* d_in, const int* in_sizes, int n_in,
                              void* d_out, int out_size, void* d_ws, size_t ws_size,
                              hipStream_t stream)
{
    const float* x    = (const float*)d_in[0];
    const int*   y    = (const int*)  d_in[1];
    const float* eWih = (const float*)d_in[2];
    const float* eWhh = (const float*)d_in[3];
    const float* ebih = (const float*)d_in[4];
    const float* ebhh = (const float*)d_in[5];
    const float* dWih = (const float*)d_in[6];
    const float* dWhh = (const float*)d_in[7];
    const float* dbih = (const float*)d_in[8];
    const float* dbhh = (const float*)d_in[9];
    const float* linW = (const float*)d_in[10];
    const float* linb = (const float*)d_in[11];
    float* out  = (float*)d_out;
    float* hsto = (float*)d_ws;   // (TDEC-1)*HID*4 = 1.64 MB scratch

    lstm_rec<<<dim3(1), dim3(NTHR), 0, stream>>>(
        x, y, eWih, eWhh, ebih, ebhh, dWih, dWhh, dbih, dbhh, hsto);

    const int nout = TDEC * NCLS;
    logits_k<<<dim3((nout + 255) / 256), dim3(256), 0, stream>>>(hsto, linW, linb, out);
}

// Round 10
// 3817.775 us; speedup vs baseline: 2.5716x; 2.5716x over previous
//
#include <hip/hip_runtime.h>

typedef _Float16 h2_t __attribute__((ext_vector_type(2)));

#define HID  100
#define TENC 4096
#define TDEC 4096
#define NCLS 6
#define NTHR 512   // 8 waves, 2/SIMD: second wave's issue covers sync/DS/tail stalls

__device__ __forceinline__ float tanh_(float v) { return 1.0f - 2.0f * __builtin_amdgcn_rcpf(1.0f + __expf(2.0f * v)); }

// lgkm-only barrier (proven v8-v13): does NOT drain vmcnt.
#define SYNC_LDS() asm volatile("s_waitcnt lgkmcnt(0)\n\ts_barrier" ::: "memory")

__device__ __forceinline__ float packh2(float a, float b) {
    h2_t p; p[0] = (_Float16)a; p[1] = (_Float16)b;
    return __builtin_bit_cast(float, p);
}

__device__ __forceinline__ float fd2(float w, float h, float acc) {
    return __builtin_amdgcn_fdot2(__builtin_bit_cast(h2_t, w),
                                  __builtin_bit_cast(h2_t, h), acc, false);
}

// quad_perm [1,0,3,2] = 0xB1 (PROVEN v8): exchange with xor-1 partner.
__device__ __forceinline__ float dppB1(float v) {
    return __builtin_bit_cast(float, __builtin_amdgcn_update_dpp(
        0, __builtin_bit_cast(int, v), 0xB1, 0xF, 0xF, true));
}
// quad_perm [2,3,0,1] = 0x4E: exchange with xor-2 partner (same mechanism class).
__device__ __forceinline__ float dpp4E(float v) {
    return __builtin_bit_cast(float, __builtin_amdgcn_update_dpp(
        0, __builtin_bit_cast(int, v), 0x4E, 0xF, 0xF, true));
}
__device__ __forceinline__ float xsum1(float v) { return v + dppB1(v); }
__device__ __forceinline__ float xsum2(float v) { return v + dpp4E(v); }

// Persistent single-workgroup LSTM, v14 — v8's VALU math on a 4-lane/cell,
// 2-wave/SIMD layout. R13 analysis: MFMA arc closed (v12 vs v13 proves the
// stall is latency exposure at 1 wave/SIMD, not spills); v8's 1000cy step =
// 640 issue + ~320 stall, and per-SIMD MAC issue (416cy of fdot2) is
// wave-count-invariant -> split each cell's k over 4 lanes (52 fdot2/lane),
// run 2 waves/SIMD so the partner wave's issue covers the stalls.
//  - k-quarter q owns aligned 8-slot groups {q,q+4,q+8} (3x ds_read_b128)
//    + pair (96+2q) (b32). Slots 100..103 hold {x0,x1,x2,1} (enc) or
//    {yf,1,0,0} (dec) staged by t==0 — proven v10-v13 mechanism, so input
//    + bias are ordinary k-slots (bias weight at k=103, h=1).
//  - reduction: xsum1 (0xB1, proven) + xsum2 (0x4E) -> all 4 lanes hold all
//    4 gate sums; lane q activates gate q (1 exp + 1 rcp each).
//  - routing (lane-verified): v1=dppB1(act): q0<-ff; v2=dpp4E(act): q0<-fg;
//    v3=dpp4E(v1): q0<-fo. c on q0; hn broadcast by one dppB1 for q1 (hsto).
__global__ __launch_bounds__(NTHR)
void lstm_rec(const float* __restrict__ x,      // [TENC*3]
              const int*   __restrict__ y,      // [TDEC]
              const float* __restrict__ eWih,   // [400*3]
              const float* __restrict__ eWhh,   // [400*HID]
              const float* __restrict__ ebih,
              const float* __restrict__ ebhh,
              const float* __restrict__ dWih,   // [400]
              const float* __restrict__ dWhh,
              const float* __restrict__ dbih,
              const float* __restrict__ dbhh,
              float* __restrict__ hsto)         // [(TDEC-1)*HID] decoder h history
{
    __shared__ __align__(16) _Float16 hbuf[2][128];  // [parity][k-slot]: 0-99 h, 100-103 input, rest 0
    __shared__ __align__(8)  uint2    xst[TENC];     // packed f16: {x0,x1},{x2,1}
    __shared__               unsigned yst[TDEC];     // packed f16: {yf,0}

    const int  t    = threadIdx.x;
    const int  q    = t & 3;        // k-quarter / gate role (== DPP quad lane)
    const int  cell = t >> 2;       // 0..127 (100 live)
    const bool live = (cell < HID);
    const bool wq0  = live && (q == 0);   // h writer (and c owner)
    const bool wq1  = live && (q == 1);   // hsto writer (decoder)

    // activation constants: gate q -> q2 is tanh, others sigmoid
    const float cs = (q == 2) ?  2.0f : -1.0f;
    const float ms = (q == 2) ? -2.0f :  1.0f;
    const float as = (q == 2) ?  1.0f :  0.0f;

    // ---- stage x (f16 pairs) and y (f16) into LDS; zero h buffers ----
    for (int i = t; i < TENC; i += NTHR) {
        const float a = x[3*i], b = x[3*i+1], cc = x[3*i+2];
        uint2 u;
        u.x = __builtin_bit_cast(unsigned, packh2(a, b));
        u.y = __builtin_bit_cast(unsigned, packh2(cc, 1.0f));
        xst[i] = u;
    }
    for (int i = t; i < TDEC; i += NTHR)
        yst[i] = __builtin_bit_cast(unsigned, packh2((float)y[i], 0.0f));
    if (t < 256) ((_Float16*)hbuf)[t] = (_Float16)0.0f;   // both parities, 128 slots each
    __syncthreads();

    // x_0 into hbuf[0][100..103] (published by the SYNC_LDS below)
    if (t == 0) {
        uint2 u;
        u.x = __builtin_bit_cast(unsigned, packh2(x[0], x[1]));
        u.y = __builtin_bit_cast(unsigned, packh2(x[2], 1.0f));
        *(uint2*)&hbuf[0][100] = u;
    }

    // ---- encoder weights: wf[gate][13 pairs] over this lane's k-quarter ----
    // j<12: k = 8*(q+4*(j>>2)) + 2*(j&3)  (all <96 -> Whh)
    // j=12: k = 96+2q  (q0/q1: Whh 96..99; q2: Wih0,Wih1; q3: Wih2, bias)
    float wf[4][13];
    #pragma unroll
    for (int r = 0; r < 4; ++r) {
        const int row = r*HID + cell;
        #pragma unroll
        for (int j = 0; j < 12; ++j) {
            const int k = 8*(q + 4*(j >> 2)) + 2*(j & 3);
            float v0 = 0.0f, v1 = 0.0f;
            if (live) { v0 = eWhh[row*HID + k]; v1 = eWhh[row*HID + k + 1]; }
            wf[r][j] = packh2(v0, v1);
        }
        {
            const int k = 96 + 2*q;
            float v0 = 0.0f, v1 = 0.0f;
            if (live) {
                v0 = (k < HID) ? eWhh[row*HID + k] : eWih[row*3 + (k - 100)];
                v1 = (k + 1 < HID) ? eWhh[row*HID + k + 1]
                   : (k + 1 < 103) ? eWih[row*3 + (k + 1 - 100)]
                   : (ebih[row] + ebhh[row]);
            }
            wf[r][12] = packh2(v0, v1);
        }
    }
    SYNC_LDS();

    float c = 0.0f;
    int p = 0;

    // ================ encoder: 4096 steps ================
    for (int s = 0; s < TENC; ++s) {
        const _Float16* hb = hbuf[p];
        float hp[13];
        {   // 3x ds_read_b128 (groups q, q+4, q+8) + 1x b32 (pair 96+2q)
            const float4 g0 = *(const float4*)&hb[8*q];
            const float4 g1 = *(const float4*)&hb[8*q + 64];
            const float4 g2 = *(const float4*)&hb[8*q + 128 - 64 + 64];  // 8*(q+8) = 8q+128? no: elements
            // NOTE: element index = 8*(q+4*gi): gi=1 -> 8q+32, gi=2 -> 8q+64
            (void)g2;
            hp[0] = g0.x; hp[1] = g0.y; hp[2] = g0.z; hp[3] = g0.w;
            const float4 g1b = *(const float4*)&hb[8*q + 32];
            hp[4] = g1b.x; hp[5] = g1b.y; hp[6] = g1b.z; hp[7] = g1b.w;
            const float4 g2b = *(const float4*)&hb[8*q + 64];
            hp[8] = g2b.x; hp[9] = g2b.y; hp[10] = g2b.z; hp[11] = g2b.w;
            hp[12] = *(const float*)&hb[96 + 2*q];
        }

        if (t == 0 && s + 1 < TENC)                   // prefetch x_{s+1}
            *(uint2*)&hbuf[p ^ 1][100] = xst[s + 1];

        float p0 = 0.0f, p1 = 0.0f, p2 = 0.0f, p3 = 0.0f;
        #pragma unroll
        for (int j = 0; j < 13; ++j) {
            p0 = fd2(wf[0][j], hp[j], p0);
            p1 = fd2(wf[1][j], hp[j], p1);
            p2 = fd2(wf[2][j], hp[j], p2);
            p3 = fd2(wf[3][j], hp[j], p3);
        }
        const float a0 = xsum2(xsum1(p0));
        const float a1 = xsum2(xsum1(p1));
        const float a2 = xsum2(xsum1(p2));
        const float a3 = xsum2(xsum1(p3));

        // lane q activates gate q
        float u = a0;
        if (q == 1) u = a1;
        if (q == 2) u = a2;
        if (q == 3) u = a3;
        const float e   = __expf(u * cs);
        const float act = __builtin_fmaf(__builtin_amdgcn_rcpf(1.0f + e), ms, as);

        const float v1 = dppB1(act);   // q0 <- ff
        const float v2 = dpp4E(act);   // q0 <- fg
        const float v3 = dpp4E(v1);    // q0 <- fo
        c = __builtin_fmaf(v1, c, act * v2);   // valid on q0 only
        const float hn = v3 * tanh_(c);
        if (wq0)
            hbuf[p ^ 1][cell] = (_Float16)hn;
        SYNC_LDS();
        p ^= 1;
    }

    // ================ transition: decoder input slot {yf0, 1, 0, 0} ================
    if (t == 0) {
        uint2 v;
        v.x = (yst[0] & 0xFFFFu) | 0x3C000000u;   // {yf0, f16(1.0)}
        v.y = 0u;
        *(uint2*)&hbuf[p][100] = v;
    }

    // ---- decoder weights (reuse wf) ----
    #pragma unroll
    for (int r = 0; r < 4; ++r) {
        const int row = r*HID + cell;
        #pragma unroll
        for (int j = 0; j < 12; ++j) {
            const int k = 8*(q + 4*(j >> 2)) + 2*(j & 3);
            float v0 = 0.0f, v1 = 0.0f;
            if (live) { v0 = dWhh[row*HID + k]; v1 = dWhh[row*HID + k + 1]; }
            wf[r][j] = packh2(v0, v1);
        }
        {
            const int k = 96 + 2*q;
            float v0 = 0.0f, v1 = 0.0f;
            if (live) {
                v0 = (k < HID) ? dWhh[row*HID + k] : (k == 100) ? dWih[row] : 0.0f;
                v1 = (k + 1 < HID) ? dWhh[row*HID + k + 1]
                   : (k + 1 == 101) ? (dbih[row] + dbhh[row]) : 0.0f;
            }
            wf[r][12] = packh2(v0, v1);
        }
    }
    SYNC_LDS();

    // ================ decoder: 4095 steps (ratio==1 -> teacher-forced) ================
    for (int s = 0; s < TDEC - 1; ++s) {
        const _Float16* hb = hbuf[p];
        float hp[13];
        {
            const float4 g0 = *(const float4*)&hb[8*q];
            hp[0] = g0.x; hp[1] = g0.y; hp[2] = g0.z; hp[3] = g0.w;
            const float4 g1 = *(const float4*)&hb[8*q + 32];
            hp[4] = g1.x; hp[5] = g1.y; hp[6] = g1.z; hp[7] = g1.w;
            const float4 g2 = *(const float4*)&hb[8*q + 64];
            hp[8] = g2.x; hp[9] = g2.y; hp[10] = g2.z; hp[11] = g2.w;
            hp[12] = *(const float*)&hb[96 + 2*q];
        }

        if (t == 0 && s + 1 < TDEC - 1) {
            uint2 v;
            v.x = (yst[s + 1] & 0xFFFFu) | 0x3C000000u;
            v.y = 0u;
            *(uint2*)&hbuf[p ^ 1][100] = v;
        }

        float p0 = 0.0f, p1 = 0.0f, p2 = 0.0f, p3 = 0.0f;
        #pragma unroll
        for (int j = 0; j < 13; ++j) {
            p0 = fd2(wf[0][j], hp[j], p0);
            p1 = fd2(wf[1][j], hp[j], p1);
            p2 = fd2(wf[2][j], hp[j], p2);
            p3 = fd2(wf[3][j], hp[j], p3);
        }
        const float a0 = xsum2(xsum1(p0));
        const float a1 = xsum2(xsum1(p1));
        const float a2 = xsum2(xsum1(p2));
        const float a3 = xsum2(xsum1(p3));

        float u = a0;
        if (q == 1) u = a1;
        if (q == 2) u = a2;
        if (q == 3) u = a3;
        const float e   = __expf(u * cs);
        const float act = __builtin_fmaf(__builtin_amdgcn_rcpf(1.0f + e), ms, as);

        const float v1 = dppB1(act);
        const float v2 = dpp4E(act);
        const float v3 = dpp4E(v1);
        c = __builtin_fmaf(v1, c, act * v2);
        const float hn  = v3 * tanh_(c);
        const float hnb = dppB1(hn);          // q1 <- q0's hn
        if (wq0)
            hbuf[p ^ 1][cell] = (_Float16)hn;
        if (wq1)
            hsto[s * HID + cell] = hnb;       // global store, never fenced in-loop
        SYNC_LDS();
        p ^= 1;
    }
    // kernel end-of-dispatch drains the hsto stores before logits_k launches
}

// Parallel logits: out[t][r] = linW[r] . h_t + linb[r], last row zeroed.
__global__ __launch_bounds__(256)
void logits_k(const float* __restrict__ hsto, const float* __restrict__ linW,
              const float* __restrict__ linb, float* __restrict__ out)
{
    const int idx = blockIdx.x * 256 + threadIdx.x;
    if (idx >= TDEC * NCLS) return;
    const int tt = idx / NCLS;
    const int r  = idx % NCLS;
    if (tt >= TDEC - 1) { out[idx] = 0.0f; return; }
    const float* h  = hsto + tt * HID;
    const float* wr = linW + r * HID;
    float a = linb[r];
    #pragma unroll 4
    for (int k = 0; k < HID; ++k) a += wr[k] * h[k];
    out[idx] = a;
}

extern "C" void kernel_launch(void* const* d_in, const int* in_sizes, int n_in,
                              void* d_out, int out_size, void* d_ws, size_t ws_size,
                              hipStream_t stream)
{
    const float* x    = (const float*)d_in[0];
    const int*   y    = (const int*)  d_in[1];
    const float* eWih = (const float*)d_in[2];
    const float* eWhh = (const float*)d_in[3];
    const float* ebih = (const float*)d_in[4];
    const float* ebhh = (const float*)d_in[5];
    const float* dWih = (const float*)d_in[6];
    const float* dWhh = (const float*)d_in[7];
    const float* dbih = (const float*)d_in[8];
    const float* dbhh = (const float*)d_in[9];
    const float* linW = (const float*)d_in[10];
    const float* linb = (const float*)d_in[11];
    float* out  = (float*)d_out;
    float* hsto = (float*)d_ws;   // (TDEC-1)*HID*4 = 1.64 MB scratch

    lstm_rec<<<dim3(1), dim3(NTHR), 0, stream>>>(
        x, y, eWih, eWhh, ebih, ebhh, dWih, dWhh, dbih, dbhh, hsto);

    const int nout = TDEC * NCLS;
    logits_k<<<dim3((nout + 255) / 256), dim3(256), 0, stream>>>(hsto, linW, linb, out);
}